// Round 7
// baseline (777.665 us; speedup 1.0000x reference)
//
#include <hip/hip_runtime.h>
#include <cmath>

typedef unsigned short u16;
typedef unsigned int   u32;
typedef short bhalf8 __attribute__((ext_vector_type(8)));
typedef float fx4    __attribute__((ext_vector_type(4)));

#define B_   4
#define S_   1024
#define D_   1024
#define H_   16
#define HD_  64
#define FF_  4096
#define NTOK (B_*S_)
#define QKVW 3072

__device__ __forceinline__ float b2f(u16 u) {
    u32 x = ((u32)u) << 16;
    return __uint_as_float(x);
}
__device__ __forceinline__ u16 f2b(float f) {
    u32 u = __float_as_uint(f);
    u32 r = (u + 0x7fffu + ((u >> 16) & 1u)) >> 16;
    return (u16)r;
}

// async global->LDS, 16B per lane; LDS dest = wave-uniform base + lane*16
#define GLDS16(g, l) __builtin_amdgcn_global_load_lds( \
    (const __attribute__((address_space(1))) void*)(g), \
    (__attribute__((address_space(3))) void*)(l), 16, 0, 0)

// ---------------------------------------------------------------------------
// Weight convert + transpose: f32 [K,N] -> bf16 [N,K] tiles of 64x64.
// Dst elem offsets: wq 0, wk 1M, wv 2M, wo 3M, W1 4M, J1 8M, W2 12M, J2 16M.
// ---------------------------------------------------------------------------
__global__ __launch_bounds__(256) void cvt_t_k(const float* __restrict__ w0, const float* __restrict__ w1,
                                               const float* __restrict__ w2, const float* __restrict__ w3,
                                               const float* __restrict__ W1p, const float* __restrict__ J1p,
                                               const float* __restrict__ W2p, const float* __restrict__ J2p,
                                               u16* __restrict__ dst) {
    __shared__ u16 L[64][65];
    int bid = blockIdx.x, tid = threadIdx.x;
    const float* src; size_t dbase; int Kd, Nd, tk, tn;
    if (bid < 1024)      { int m = bid >> 8, t = bid & 255;
                           src = m == 0 ? w0 : m == 1 ? w1 : m == 2 ? w2 : w3;
                           dbase = (size_t)m << 20; Kd = 1024; Nd = 1024; tk = t >> 4; tn = t & 15; }
    else if (bid < 2048) { int t = bid - 1024; src = W1p; dbase = (size_t)4  << 20; Kd = 1024; Nd = 4096; tk = t >> 6; tn = t & 63; }
    else if (bid < 3072) { int t = bid - 2048; src = J1p; dbase = (size_t)8  << 20; Kd = 1024; Nd = 4096; tk = t >> 6; tn = t & 63; }
    else if (bid < 4096) { int t = bid - 3072; src = W2p; dbase = (size_t)12 << 20; Kd = 4096; Nd = 1024; tk = t >> 4; tn = t & 15; }
    else                 { int t = bid - 4096; src = J2p; dbase = (size_t)16 << 20; Kd = 4096; Nd = 1024; tk = t >> 4; tn = t & 15; }
    int k0 = tk * 64, n0 = tn * 64;
    int r = tid >> 2, c4 = (tid & 3) * 16;
    #pragma unroll
    for (int p = 0; p < 4; ++p) {
        float4 v = *(const float4*)&src[(size_t)(k0 + r) * Nd + n0 + c4 + p * 4];
        L[r][c4 + p * 4 + 0] = f2b(v.x);
        L[r][c4 + p * 4 + 1] = f2b(v.y);
        L[r][c4 + p * 4 + 2] = f2b(v.z);
        L[r][c4 + p * 4 + 3] = f2b(v.w);
    }
    __syncthreads();
    u16 o[16];
    #pragma unroll
    for (int j = 0; j < 16; ++j) o[j] = L[c4 + j][r];
    *(uint4*)&dst[dbase + (size_t)(n0 + r) * Kd + k0 + c4]     = *(uint4*)&o[0];
    *(uint4*)&dst[dbase + (size_t)(n0 + r) * Kd + k0 + c4 + 8] = *(uint4*)&o[8];
}

// elementwise in-place tanh over bf16 buffer, 8 elems/thread
__global__ __launch_bounds__(256) void tanh_k(u16* __restrict__ buf) {
    size_t idx = ((size_t)blockIdx.x * 256 + threadIdx.x) * 8;
    uint4 v = *(uint4*)&buf[idx];
    const u16* p = (const u16*)&v;
    u16 o[8];
    #pragma unroll
    for (int j = 0; j < 8; ++j) o[j] = f2b(tanhf(b2f(p[j])));
    *(uint4*)&buf[idx] = *(uint4*)o;
}

// ---------------------------------------------------------------------------
// BMx128 MFMA GEMM (m97 structure): C[M,N] = A[M,K] @ Bt[N,K]^T + bias
//   BM: 128 (waves 2x2 of 64x64) or 64 (waves 2x2 of 32x64; grid 2x for
//       occupancy on N=1024 shapes whose 128-tile grid is 1 block/CU)
//   EPI 0: store bf16(acc+bias)
//   EPI 1: store f32(acc+bias+resid)        (x + attn@wo)
//   EPI 2: ht=Cout[idx]; Cout=bf16(ht+0.5*acc*tanh(ht))   (QBNN combine)
//   SEG: bias segmented per 1024 cols (fused QKV)
// ---------------------------------------------------------------------------
template <int BM, int EPI, bool SEG>
__global__ __launch_bounds__(256) void gemm_t(const u16* __restrict__ A,
                                              const u16* __restrict__ Bt,
                                              const float* __restrict__ bA,
                                              const float* __restrict__ bB,
                                              const float* __restrict__ bC,
                                              const float* __restrict__ resid,
                                              void* __restrict__ Cout,
                                              int M, int N, int K) {
    constexpr int MT = BM / 32;          // row tiles per wave
    __shared__ u16 As[BM * 32];
    __shared__ u16 Bs[128 * 32];
    const int tid = threadIdx.x;
    const int w = tid >> 6, ln = tid & 63;
    const int q = ln >> 4, mr = ln & 15;
    const int m0 = blockIdx.y * BM, n0 = blockIdx.x * 128;
    const int wm = (w >> 1) * (BM / 2), wn = (w & 1) * 64;
    const int sr = w * 16 + (ln >> 2);
    const int sc = (ln & 3) * 8;

    fx4 acc[MT][4];
    #pragma unroll
    for (int i = 0; i < MT; ++i)
        #pragma unroll
        for (int j = 0; j < 4; ++j) acc[i][j] = (fx4){0.f, 0.f, 0.f, 0.f};

    const u16* Ab0 = A  + (size_t)(m0 + sr) * K + sc;
    const u16* Ab1 = A  + (size_t)(m0 + sr + 64) * K + sc;   // BM==128 only
    const u16* Bb0 = Bt + (size_t)(n0 + sr) * K + sc;
    const u16* Bb1 = Bt + (size_t)(n0 + sr + 64) * K + sc;

    for (int k0 = 0; k0 < K; k0 += 32) {
        __syncthreads();
        GLDS16(Ab0 + k0, &As[w * 512]);
        if (BM == 128) GLDS16(Ab1 + k0, &As[(w + 4) * 512]);
        GLDS16(Bb0 + k0, &Bs[w * 512]);
        GLDS16(Bb1 + k0, &Bs[(w + 4) * 512]);
        __syncthreads();

        bhalf8 af[MT], bf[4];
        #pragma unroll
        for (int i = 0; i < MT; ++i) af[i] = *(const bhalf8*)&As[(wm + i * 16 + mr) * 32 + q * 8];
        #pragma unroll
        for (int j = 0; j < 4; ++j) bf[j] = *(const bhalf8*)&Bs[(wn + j * 16 + mr) * 32 + q * 8];
        #pragma unroll
        for (int i = 0; i < MT; ++i)
            #pragma unroll
            for (int j = 0; j < 4; ++j)
                acc[i][j] = __builtin_amdgcn_mfma_f32_16x16x32_bf16(af[i], bf[j], acc[i][j], 0, 0, 0);
    }

    #pragma unroll
    for (int j = 0; j < 4; ++j) {
        int col = n0 + wn + j * 16 + mr;
        float bs;
        if (SEG) {
            const float* bp = col < 1024 ? bA : (col < 2048 ? bB : bC);
            bs = bp[col & 1023];
        } else {
            bs = bA ? bA[col] : 0.f;
        }
        #pragma unroll
        for (int i = 0; i < MT; ++i) {
            #pragma unroll
            for (int r = 0; r < 4; ++r) {
                int row    = m0 + wm + i * 16 + q * 4 + r;
                size_t idx = (size_t)row * N + col;
                float v    = acc[i][j][r] + bs;
                if (EPI == 0) {
                    ((u16*)Cout)[idx] = f2b(v);
                } else if (EPI == 1) {
                    ((float*)Cout)[idx] = v + resid[idx];
                } else {
                    float ht = b2f(((u16*)Cout)[idx]);
                    ((u16*)Cout)[idx] = f2b(ht + 0.5f * v * tanhf(ht));
                }
            }
        }
    }
}

// ---------------------------------------------------------------------------
// LayerNorm over f32 input rows -> bf16 out.
// ---------------------------------------------------------------------------
__global__ __launch_bounds__(256) void ln_k(const float* __restrict__ xin,
                                            const float* __restrict__ g,
                                            const float* __restrict__ bb,
                                            u16* __restrict__ out, int W) {
    __shared__ float red[8], red2[8], stats[2];
    int row = blockIdx.x, tid = threadIdx.x;
    float s = 0.f, ss = 0.f;
    for (int c = tid; c < W; c += 256) {
        float v = xin[(size_t)row * W + c];
        s += v; ss += v * v;
    }
    #pragma unroll
    for (int off = 32; off; off >>= 1) { s += __shfl_xor(s, off); ss += __shfl_xor(ss, off); }
    int wave = tid >> 6, lane = tid & 63;
    if (lane == 0) { red[wave] = s; red2[wave] = ss; }
    __syncthreads();
    if (tid == 0) {
        float S = 0.f, SS = 0.f;
        for (int w2 = 0; w2 < 4; ++w2) { S += red[w2]; SS += red2[w2]; }
        float mu = S / W;
        stats[0] = mu;
        stats[1] = rsqrtf(SS / W - mu * mu + 1e-5f);
    }
    __syncthreads();
    float mu = stats[0], rs = stats[1];
    for (int c = tid; c < W; c += 256)
        out[(size_t)row * W + c] = f2b((xin[(size_t)row * W + c] - mu) * rs * g[c] + bb[c]);
}

// ---------------------------------------------------------------------------
// LN + exact GELU over bf16 rows u. RES: add f32 resid. OUT_F32: f32 out.
// In-place safe: all u reads precede the barrier before writes.
// ---------------------------------------------------------------------------
template <bool RES, bool OUT_F32>
__global__ __launch_bounds__(256) void lngelu_k(const u16* __restrict__ u,
                                                const float* __restrict__ g,
                                                const float* __restrict__ be,
                                                const float* __restrict__ resid,
                                                void* __restrict__ out, int W) {
    __shared__ float ub[4096];
    __shared__ float red[8], red2[8], stats[2];
    int row = blockIdx.x, tid = threadIdx.x;
    float s = 0.f, ss = 0.f;
    for (int c = tid; c < W; c += 256) {
        float v = b2f(u[(size_t)row * W + c]);
        ub[c] = v; s += v; ss += v * v;
    }
    #pragma unroll
    for (int off = 32; off; off >>= 1) { s += __shfl_xor(s, off); ss += __shfl_xor(ss, off); }
    int wave = tid >> 6, lane = tid & 63;
    if (lane == 0) { red[wave] = s; red2[wave] = ss; }
    __syncthreads();
    if (tid == 0) {
        float S = 0.f, SS = 0.f;
        for (int w2 = 0; w2 < 4; ++w2) { S += red[w2]; SS += red2[w2]; }
        float mu = S / W;
        stats[0] = mu;
        stats[1] = rsqrtf(SS / W - mu * mu + 1e-5f);
    }
    __syncthreads();
    float mu = stats[0], rs = stats[1];
    for (int c = tid; c < W; c += 256) {
        float v = (ub[c] - mu) * rs * g[c] + be[c];
        float y = 0.5f * v * (1.f + erff(v * 0.70710678118654752f));
        if (RES) y += resid[(size_t)row * W + c];
        if (OUT_F32) ((float*)out)[(size_t)row * W + c] = y;
        else         ((u16*)out)[(size_t)row * W + c] = f2b(y);
    }
}

// ---------------------------------------------------------------------------
// Qaug[B,H,S,128]: [0:64]=Q/8, [64:128]=lam*(tanh(Q)@J[h]).
// Q lives in fused QKV buffer [NTOK, 3072], cols [0,1024).
// ---------------------------------------------------------------------------
__global__ __launch_bounds__(256) void aug_q_k(const u16* __restrict__ QKV,
                                               const float* __restrict__ J,
                                               const float* __restrict__ lamp,
                                               u16* __restrict__ QA) {
    __shared__ float Jl[64][65];
    __shared__ float Tq[64][65];
    int blk = blockIdx.x;
    int bh = blk >> 4, st = blk & 15;
    int b = bh >> 4, h = bh & 15;
    int s0 = st * 64;
    int tid = threadIdx.x;
    float lam = lamp[0];

    for (int i = tid; i < 4096; i += 256)
        Jl[i >> 6][i & 63] = J[h * 4096 + i];
    for (int i = tid; i < 4096; i += 256) {
        int r = i >> 6, c = i & 63;
        float v  = b2f(QKV[(size_t)(b * S_ + s0 + r) * QKVW + h * 64 + c]);
        Tq[r][c] = tanhf(v);
        QA[((size_t)(bh * S_ + s0 + r)) * 128 + c] = f2b(v * 0.125f);  // /sqrt(64)
    }
    __syncthreads();

    int r = tid >> 2, c0 = (tid & 3) * 16;
    float acc[16];
    #pragma unroll
    for (int j = 0; j < 16; ++j) acc[j] = 0.f;
    for (int k = 0; k < 64; ++k) {
        float a = Tq[r][k];
        #pragma unroll
        for (int j = 0; j < 16; ++j) acc[j] += a * Jl[k][c0 + j];
    }
    size_t orow = ((size_t)(bh * S_ + s0 + r)) * 128 + 64 + c0;
    #pragma unroll
    for (int j = 0; j < 16; ++j) QA[orow + j] = f2b(lam * acc[j]);
}

// Kaug[B,H,S,128]: [0:64]=K, [64:128]=tanh(K). K in QKV cols [1024,2048).
__global__ __launch_bounds__(256) void aug_k_k(const u16* __restrict__ QKV,
                                               u16* __restrict__ KA) {
    int idx = blockIdx.x * 256 + threadIdx.x;  // < B*S*D
    int d = idx & (D_ - 1);
    int bs = idx >> 10;
    int h = d >> 6, hd = d & 63;
    int b = bs >> 10, si = bs & (S_ - 1);
    u16 v      = QKV[(size_t)bs * QKVW + 1024 + d];
    size_t row = (size_t)((b * H_ + h) * S_ + si);
    KA[row * 128 + hd]      = v;
    KA[row * 128 + 64 + hd] = f2b(tanhf(b2f(v)));
}

// ---------------------------------------------------------------------------
// MFMA flash attention. V in QKV cols [2048,3072).
// Q fragments are loop-invariant -> staged once via Ks buffer into registers;
// LDS is then only Ks+Vt+Ps (36 KB -> 4 blocks/CU vs 53 KB/2 before).
// ---------------------------------------------------------------------------
#define QS_STRIDE 136
#define PS_STRIDE 72
__global__ __launch_bounds__(256) void attn_k(const u16* __restrict__ QA,
                                              const u16* __restrict__ KA,
                                              const u16* __restrict__ QKV,
                                              u16* __restrict__ out) {
    __shared__ u16 Ks[64 * QS_STRIDE];
    __shared__ u16 Vt[64 * PS_STRIDE];
    __shared__ u16 Ps[4 * 16 * PS_STRIDE];

    const int tid  = threadIdx.x;
    const int w    = tid >> 6, lane = tid & 63;
    const int q    = lane >> 4, mr = lane & 15;
    const int bh   = blockIdx.x >> 4;
    const int qt   = blockIdx.x & 15;
    const int b    = bh >> 4, h = bh & 15;

    // stage Q tile into Ks, pull fragments to registers, then release LDS
    #pragma unroll
    for (int p = 0; p < 4; ++p) {
        int idx = p * 2048 + tid * 8;
        int row = idx >> 7, col = idx & 127;
        uint4 v4 = *(const uint4*)&QA[((size_t)(bh * S_ + qt * 64 + row)) * 128 + col];
        *(uint4*)&Ks[row * QS_STRIDE + col] = v4;
    }
    __syncthreads();
    bhalf8 afr[4];
    #pragma unroll
    for (int ks = 0; ks < 4; ++ks)
        afr[ks] = *(const bhalf8*)&Ks[(w * 16 + mr) * QS_STRIDE + ks * 32 + q * 8];
    __syncthreads();

    fx4 zero = {0.f, 0.f, 0.f, 0.f};
    fx4 O[4] = {zero, zero, zero, zero};
    float m[4]  = {-3e38f, -3e38f, -3e38f, -3e38f};
    float l[4]  = {0.f, 0.f, 0.f, 0.f};

    for (int kt = 0; kt < 16; ++kt) {
        #pragma unroll
        for (int p = 0; p < 4; ++p) {
            int idx = p * 2048 + tid * 8;
            int row = idx >> 7, col = idx & 127;
            uint4 v4 = *(const uint4*)&KA[((size_t)(bh * S_ + kt * 64 + row)) * 128 + col];
            *(uint4*)&Ks[row * QS_STRIDE + col] = v4;
        }
        #pragma unroll
        for (int p = 0; p < 2; ++p) {
            int idx = p * 2048 + tid * 8;
            int key = idx >> 6, d0 = idx & 63;
            uint4 v4 = *(const uint4*)&QKV[((size_t)(b * S_ + kt * 64 + key)) * QKVW + 2048 + h * 64 + d0];
            const u16* vp = (const u16*)&v4;
            #pragma unroll
            for (int j = 0; j < 8; ++j) Vt[(d0 + j) * PS_STRIDE + key] = vp[j];
        }
        __syncthreads();

        fx4 St[4] = {zero, zero, zero, zero};
        #pragma unroll
        for (int nt = 0; nt < 4; ++nt) {
            #pragma unroll
            for (int ks = 0; ks < 4; ++ks) {
                bhalf8 bf = *(const bhalf8*)&Ks[(nt * 16 + mr) * QS_STRIDE + ks * 32 + q * 8];
                St[nt] = __builtin_amdgcn_mfma_f32_16x16x32_bf16(afr[ks], bf, St[nt], 0, 0, 0);
            }
        }

        float alpha[4];
        #pragma unroll
        for (int r = 0; r < 4; ++r) {
            float mx = fmaxf(fmaxf(St[0][r], St[1][r]), fmaxf(St[2][r], St[3][r]));
            #pragma unroll
            for (int off = 8; off; off >>= 1) mx = fmaxf(mx, __shfl_xor(mx, off));
            float nm = fmaxf(m[r], mx);
            alpha[r] = __expf(m[r] - nm);
            m[r] = nm;
            float ps = 0.f;
            #pragma unroll
            for (int nt = 0; nt < 4; ++nt) {
                float p = __expf(St[nt][r] - nm);
                St[nt][r] = p;
                ps += p;
            }
            #pragma unroll
            for (int off = 8; off; off >>= 1) ps += __shfl_xor(ps, off);
            l[r] = l[r] * alpha[r] + ps;
        }
        #pragma unroll
        for (int nt = 0; nt < 4; ++nt) {
            #pragma unroll
            for (int r = 0; r < 4; ++r) {
                Ps[(w * 16 + q * 4 + r) * PS_STRIDE + nt * 16 + mr] = f2b(St[nt][r]);
                O[nt][r] *= alpha[r];
            }
        }

        #pragma unroll
        for (int ks = 0; ks < 2; ++ks) {
            bhalf8 pa = *(const bhalf8*)&Ps[(w * 16 + mr) * PS_STRIDE + ks * 32 + q * 8];
            #pragma unroll
            for (int nt = 0; nt < 4; ++nt) {
                bhalf8 bf = *(const bhalf8*)&Vt[(nt * 16 + mr) * PS_STRIDE + ks * 32 + q * 8];
                O[nt] = __builtin_amdgcn_mfma_f32_16x16x32_bf16(pa, bf, O[nt], 0, 0, 0);
            }
        }
        __syncthreads();
    }

    #pragma unroll
    for (int nt = 0; nt < 4; ++nt) {
        int d = nt * 16 + mr;
        #pragma unroll
        for (int r = 0; r < 4; ++r) {
            int row = qt * 64 + w * 16 + q * 4 + r;
            out[((size_t)(b * S_ + row)) * D_ + h * 64 + d] = f2b(O[nt][r] / l[r]);
        }
    }
}

// ---------------------------------------------------------------------------
// Workspace (104 MB peak; live ranges verified):
//   [  0, 40)  WB: bf16 weights TRANSPOSED [N,K] — live whole launch
//   [ 40, 48)  XN(1-2) -> AT(4-5) -> U2(8-9)
//   [ 48, 72)  QKV fused [NTOK,3072] (2-4) -> Hb[48,56)(6-7) + X2 f32[56,72)(5-9)
//   [ 72,104)  QA[72,88)+KA[88,104)(3-4) -> U1(7-9)
// ---------------------------------------------------------------------------
extern "C" void kernel_launch(void* const* d_in, const int* in_sizes, int n_in,
                              void* d_out, int out_size, void* d_ws, size_t ws_size,
                              hipStream_t stream) {
    const float* x      = (const float*)d_in[0];
    const float* wq     = (const float*)d_in[1];
    const float* bq     = (const float*)d_in[2];
    const float* wk     = (const float*)d_in[3];
    const float* bk     = (const float*)d_in[4];
    const float* wv     = (const float*)d_in[5];
    const float* bv     = (const float*)d_in[6];
    const float* wo     = (const float*)d_in[7];
    const float* bo     = (const float*)d_in[8];
    const float* Jattn  = (const float*)d_in[9];
    const float* lamA   = (const float*)d_in[10];
    const float* g_attn = (const float*)d_in[11];
    const float* b_attn = (const float*)d_in[12];
    const float* W1     = (const float*)d_in[13];
    const float* b1     = (const float*)d_in[14];
    const float* J1     = (const float*)d_in[15];
    const float* g1     = (const float*)d_in[17];
    const float* be1    = (const float*)d_in[18];
    const float* W2     = (const float*)d_in[19];
    const float* b2     = (const float*)d_in[20];
    const float* J2     = (const float*)d_in[21];
    const float* g2     = (const float*)d_in[23];
    const float* be2    = (const float*)d_in[24];
    const float* g_ffn  = (const float*)d_in[25];
    const float* b_ffn  = (const float*)d_in[26];
    float* out = (float*)d_out;
    (void)ws_size; (void)in_sizes; (void)n_in; (void)out_size;

    char* wsp = (char*)d_ws;
    const size_t MB = 1u << 20;
    u16* WB = (u16*)(wsp);
    const u16* qkvT = WB;                        // wq|wk|wv transposed, [3072,1024]
    const u16* woT  = WB + ((size_t)3 << 20);
    const u16* W1T  = WB + ((size_t)4 << 20);
    const u16* J1T  = WB + ((size_t)8 << 20);
    const u16* W2T  = WB + ((size_t)12 << 20);
    const u16* J2T  = WB + ((size_t)16 << 20);
    u16*   XN   = (u16*)(wsp + 40 * MB);
    u16*   AT   = (u16*)(wsp + 40 * MB);
    u16*   U2   = (u16*)(wsp + 40 * MB);
    u16*   QKVb = (u16*)(wsp + 48 * MB);
    u16*   Hb   = (u16*)(wsp + 48 * MB);
    float* X2   = (float*)(wsp + 56 * MB);
    u16*   QA   = (u16*)(wsp + 72 * MB);
    u16*   KA   = (u16*)(wsp + 88 * MB);
    u16*   U1   = (u16*)(wsp + 72 * MB);

    dim3 blk(256);
    // 0) weights f32 -> bf16, transposed to [N,K]
    cvt_t_k<<<5120, blk, 0, stream>>>(wq, wk, wv, wo, W1, J1, W2, J2, WB);
    // 1) attention pre-norm
    ln_k<<<NTOK, blk, 0, stream>>>(x, g_attn, b_attn, XN, D_);
    // 2) fused QKV projection: [NTOK,3072]  (grid 768 = 3 blocks/CU)
    gemm_t<128, 0, true><<<dim3(QKVW / 128, NTOK / 128), blk, 0, stream>>>(XN, qkvT, bq, bk, bv, nullptr, QKVb, NTOK, QKVW, D_);
    // 3) augmented heads
    aug_q_k<<<B_ * H_ * (S_ / 64), blk, 0, stream>>>(QKVb, Jattn, lamA, QA);
    aug_k_k<<<(NTOK * D_) / 256, blk, 0, stream>>>(QKVb, KA);
    // 4) MFMA flash attention
    attn_k<<<B_ * H_ * (S_ / 64), blk, 0, stream>>>(QA, KA, QKVb, AT);
    // 5) output projection + residual -> f32 trunk X2  (BM=64: grid 512 = 2/CU)
    gemm_t<64, 1, false><<<dim3(D_ / 128, NTOK / 64), blk, 0, stream>>>(AT, woT, bo, nullptr, nullptr, x, X2, NTOK, D_, D_);
    // 6) ffn pre-norm
    ln_k<<<NTOK, blk, 0, stream>>>(X2, g_ffn, b_ffn, Hb, D_);
    // 7) QBNN layer 1: W-pass -> U1; tanh(Hb) in place; J-pass combine; LN+GELU
    gemm_t<128, 0, false><<<dim3(FF_ / 128, NTOK / 128), blk, 0, stream>>>(Hb, W1T, b1, nullptr, nullptr, nullptr, U1, NTOK, FF_, D_);
    tanh_k<<<(NTOK * D_) / 2048, blk, 0, stream>>>(Hb);
    gemm_t<128, 2, false><<<dim3(FF_ / 128, NTOK / 128), blk, 0, stream>>>(Hb, J1T, nullptr, nullptr, nullptr, nullptr, U1, NTOK, FF_, D_);
    lngelu_k<false, false><<<NTOK, blk, 0, stream>>>(U1, g1, be1, nullptr, U1, FF_);
    // 8) QBNN layer 2 (BM=64: grid 512 = 2/CU): W-pass -> U2; tanh; J-pass; LN+GELU+resid
    gemm_t<64, 0, false><<<dim3(D_ / 128, NTOK / 64), blk, 0, stream>>>(U1, W2T, b2, nullptr, nullptr, nullptr, U2, NTOK, D_, FF_);
    tanh_k<<<(NTOK * FF_) / 2048, blk, 0, stream>>>(U1);
    gemm_t<64, 2, false><<<dim3(D_ / 128, NTOK / 64), blk, 0, stream>>>(U1, J2T, nullptr, nullptr, nullptr, nullptr, U2, NTOK, D_, FF_);
    lngelu_k<true, true><<<NTOK, blk, 0, stream>>>(U2, g2, be2, X2, out, D_);
}